// Round 5
// baseline (2042.526 us; speedup 1.0000x reference)
//
#include <hip/hip_runtime.h>
#include <cstdint>
#include <cstddef>

#define DI __device__ __forceinline__

typedef unsigned short u16;
typedef u16 u16x8 __attribute__((ext_vector_type(8)));
typedef u16 u16x4 __attribute__((ext_vector_type(4)));
typedef float f32x4 __attribute__((ext_vector_type(4)));
typedef __bf16 bf16x8 __attribute__((ext_vector_type(8)));

constexpr float EPSf  = 1e-5f;
constexpr float SCALE = 1.0f / (5.656854249492381f * 256.0f); // 1/(sqrt(32)*H*W)

DI float bf2f(u16 u) { union { uint32_t i; float f; } v; v.i = ((uint32_t)u) << 16; return v.f; }
DI u16 f2bf(float f) {
    union { float f; uint32_t i; } v; v.f = f;
    uint32_t r = v.i + 0x7fffu + ((v.i >> 16) & 1u);
    return (u16)(r >> 16);
}
DI bf16x8 u2b(u16x8 u) { union { u16x8 a; bf16x8 b; } v; v.a = u; return v.b; }

DI f32x4 MFMA(bf16x8 a, bf16x8 b, f32x4 c) {
    return __builtin_amdgcn_mfma_f32_16x16x32_bf16(a, b, c, 0, 0, 0);
}

DI int region3(int x) { return x < 12 ? 0 : (x < 14 ? 1 : 2); }

// fast tanh-gelu: 0.5x(1+tanh(s(x+0.044715x^3))) == x*sigmoid(2s(x+...))
DI float gelu_f(float x) {
    float u = 1.5957691216f * x * (1.f + 0.044715f * x * x);
    return x * __builtin_amdgcn_rcpf(1.f + __expf(-u));
}

// ---------------------------------------------------------------------------
// KW: transpose 6 weights [c][d] f32 -> WT [d][c] bf16
// ---------------------------------------------------------------------------
__global__ __launch_bounds__(256) void kw_prep(
        const float* __restrict__ w_q, const float* __restrict__ w_k,
        const float* __restrict__ w_v, const float* __restrict__ w_o,
        const float* __restrict__ w1,  const float* __restrict__ w2,
        u16* __restrict__ wt) {
    __shared__ float lds[128 * 129];
    const float* W;
    switch (blockIdx.x) {
        case 0: W = w_q; break; case 1: W = w_k; break; case 2: W = w_v; break;
        case 3: W = w_o; break; case 4: W = w1;  break; default: W = w2;  break;
    }
    u16* O = wt + blockIdx.x * 16384;
    int tid = threadIdx.x;
    for (int i = 0; i < 16; i++) {
        int flat = i * 1024 + tid * 4;
        float4 vv = *(const float4*)(W + flat);
        int c = flat >> 7, d = flat & 127;
        lds[c * 129 + d + 0] = vv.x; lds[c * 129 + d + 1] = vv.y;
        lds[c * 129 + d + 2] = vv.z; lds[c * 129 + d + 3] = vv.w;
    }
    __syncthreads();
    for (int i = 0; i < 32; i++) {
        int flat2 = i * 512 + tid * 2;
        int d = flat2 >> 7, c = flat2 & 127;
        u16 a = f2bf(lds[c * 129 + d]);
        u16 b = f2bf(lds[(c + 1) * 129 + d]);
        uint32_t pk = (uint32_t)a | ((uint32_t)b << 16);
        *(uint32_t*)(O + flat2) = pk;
    }
}

// ---------------------------------------------------------------------------
// K2: per windowed-token. Coalesced 16B/lane loads, raw bf16 to LDS [c][xy]
//     pitch 268, stats via contiguous row reads, normalize folded into A-frag
//     regs. GEMM x3 with B-frags DIRECT from global (L2-hot 96KB weights) ->
//     the whole GEMM+epilogue phase is barrier-free (4 barriers total).
// ---------------------------------------------------------------------------
__global__ __launch_bounds__(512, 4) void k2_qkv(
        const float* __restrict__ v, const u16* __restrict__ wt,
        const float* __restrict__ b_q, const float* __restrict__ b_k,
        const float* __restrict__ b_v,
        u16* __restrict__ Qg, u16* __restrict__ Kg, u16* __restrict__ Vg) {
    __shared__ __align__(16) u16 Raw[34816];   // [c 128][xy] pitch 268 (34304 used)
    __shared__ float red[2][4][128];
    __shared__ float stats[2][128];

    int tid = threadIdx.x;
    int wtk = blockIdx.x;                       // windowed token id
    int b = wtk >> 8, n = (wtk >> 4) & 15, t = wtk & 15;
    int wi = n >> 2, wj = n & 3, ti = t >> 2, tj = t & 3;
    int si = (wi * 4 + ti + 2) & 15, sj = (wj * 4 + tj + 2) & 15; // roll -2
    const float* src = v + (size_t)(b * 256 + si * 16 + sj) * 32768;

    int wave = tid >> 6, lane = tid & 63;

    // load: wave w iter i covers channel c = i*8+w; lane reads 16B contiguous
    #pragma unroll
    for (int i = 0; i < 16; i++) {
        int c = i * 8 + wave;
        float4 f = *(const float4*)(src + c * 256 + lane * 4);
        u16x4 u; u.x = f2bf(f.x); u.y = f2bf(f.y); u.z = f2bf(f.z); u.w = f2bf(f.w);
        *(u16x4*)&Raw[c * 268 + lane * 4] = u;
    }
    __syncthreads();
    // stats: contiguous row reads (b64), per (c, quarter)
    {
        int c = tid & 127, p = tid >> 7;
        float s = 0.f, q = 0.f;
        #pragma unroll
        for (int k = 0; k < 16; k++) {
            u16x4 u = *(const u16x4*)&Raw[c * 268 + p * 64 + k * 4];
            float x0 = bf2f(u.x), x1 = bf2f(u.y), x2 = bf2f(u.z), x3 = bf2f(u.w);
            s += x0 + x1 + x2 + x3;
            q += x0 * x0 + x1 * x1 + x2 * x2 + x3 * x3;
        }
        red[0][p][c] = s; red[1][p][c] = q;
    }
    __syncthreads();
    if (tid < 128) {
        int c = tid;
        float s = red[0][0][c] + red[0][1][c] + red[0][2][c] + red[0][3][c];
        float q = red[1][0][c] + red[1][1][c] + red[1][2][c] + red[1][3][c];
        float mean = s * (1.f / 256.f);
        float var = q * (1.f / 256.f) - mean * mean;
        float a = rsqrtf(var + EPSf);
        stats[0][c] = a; stats[1][c] = -mean * a;
    }
    __syncthreads();

    // A-frag extraction with in-register normalization
    int lrow = lane & 15, quad = lane >> 4;
    bf16x8 afr[2][4];
    #pragma unroll
    for (int kt = 0; kt < 4; kt++) {
        float sa[8], sb[8];
        #pragma unroll
        for (int j = 0; j < 8; j++) {
            int c = kt * 32 + quad * 8 + j;
            sa[j] = stats[0][c]; sb[j] = stats[1][c];
        }
        #pragma unroll
        for (int mi = 0; mi < 2; mi++) {
            int xy = (wave * 2 + mi) * 16 + lrow;
            u16x8 o;
            #pragma unroll
            for (int j = 0; j < 8; j++) {
                int c = kt * 32 + quad * 8 + j;
                o[j] = f2bf(fmaf(bf2f(Raw[c * 268 + xy]), sa[j], sb[j]));
            }
            afr[mi][kt] = u2b(o);
        }
    }
    __syncthreads();   // all waves extracted; Raw becomes per-wave staging

    u16* stgw = Raw + wave * 2176;       // per-wave 16 x pitch 136
    for (int w = 0; w < 3; w++) {
        const u16* WTp = wt + w * 16384;
        const float* bias = (w == 0) ? b_q : (w == 1) ? b_k : b_v;
        u16* O = ((w == 0) ? Qg : (w == 1) ? Kg : Vg) + (size_t)wtk * 32768;
        f32x4 acc[2][8];
        #pragma unroll
        for (int mi = 0; mi < 2; mi++)
            #pragma unroll
            for (int nt = 0; nt < 8; nt++) acc[mi][nt] = (f32x4){0.f, 0.f, 0.f, 0.f};
        #pragma unroll
        for (int kt = 0; kt < 4; kt++) {
            #pragma unroll
            for (int nt = 0; nt < 8; nt++) {
                bf16x8 bfr = *(const bf16x8*)&WTp[(nt * 16 + lrow) * 128 + kt * 32 + quad * 8];
                acc[0][nt] = MFMA(afr[0][kt], bfr, acc[0][nt]);
                acc[1][nt] = MFMA(afr[1][kt], bfr, acc[1][nt]);
            }
        }
        #pragma unroll
        for (int mi = 0; mi < 2; mi++) {
            int mt = wave * 2 + mi;
            #pragma unroll
            for (int nt = 0; nt < 8; nt++) {
                int d = nt * 16 + lrow;
                float bv = bias[d];
                #pragma unroll
                for (int r = 0; r < 4; r++)
                    stgw[(quad * 4 + r) * 136 + d] = f2bf(acc[mi][nt][r] + bv);
            }
            // wave-local staging: no barrier needed
            #pragma unroll
            for (int ro = 0; ro < 4; ro++) {
                int flat = ro * 512 + lane * 8;
                *(u16x8*)&O[mt * 2048 + flat] =
                    *(const u16x8*)&stgw[(flat >> 7) * 136 + (flat & 127)];
            }
        }
    }
}

// ---------------------------------------------------------------------------
// K3: partial scores per (b, window, xy-half). Fragments straight from global.
//     16 waves = 4 heads x 4 xy-subchunks; cross-wave f32x4 reduce in LDS.
// ---------------------------------------------------------------------------
__global__ __launch_bounds__(1024, 4) void k3_scores(
        const u16* __restrict__ Qg, const u16* __restrict__ Kg,
        float* __restrict__ spart) {
    __shared__ f32x4 red3[3][4][64];
    int tid = threadIdx.x;
    int bid = blockIdx.x;                   // 256 = b(8) * n(16) * half(2)
    int b = bid >> 5, n = (bid >> 1) & 15, half = bid & 1;
    int wtb = (b * 16 + n) * 16;
    int lane = tid & 63, wave = tid >> 6;   // 16 waves
    int head = wave & 3, sub = wave >> 2;   // head 0..3, xy-subchunk 0..3
    int lrow = lane & 15, quad = lane >> 4;
    int xyb = half * 128 + sub * 32;
    const u16* Qp = Qg + (size_t)(wtb + lrow) * 32768 + (size_t)xyb * 128 + head * 32 + quad * 8;
    const u16* Kp = Kg + (size_t)(wtb + lrow) * 32768 + (size_t)xyb * 128 + head * 32 + quad * 8;
    f32x4 acc = {0.f, 0.f, 0.f, 0.f};
    #pragma unroll 4
    for (int kt = 0; kt < 32; kt++) {
        bf16x8 aq = *(const bf16x8*)(Qp + kt * 128);
        bf16x8 bk = *(const bf16x8*)(Kp + kt * 128);
        acc = MFMA(aq, bk, acc);
    }
    if (sub) red3[sub - 1][head][lane] = acc;
    __syncthreads();
    if (sub == 0) {
        f32x4 a0 = red3[0][head][lane];
        f32x4 a1 = red3[1][head][lane];
        f32x4 a2 = red3[2][head][lane];
        acc = acc + a0 + a1 + a2;
        float* sp = spart + (size_t)(((half * 8 + b) * 16 + n) * 4 + head) * 256;
        for (int r = 0; r < 4; r++) sp[(quad * 4 + r) * 16 + lrow] = acc[r];
    }
}

// ---------------------------------------------------------------------------
// K4: softmax+mask, PV direct-from-global into MFMA A-frags, Wo GEMM
//     (B direct), + residual v -> v2 bf16 [tok][xy][c].
//     ONE barrier total; sub-loop fully barrier-free; per-wave LDS staging.
// ---------------------------------------------------------------------------
__global__ __launch_bounds__(512, 4) void k4_attnout(
        const float* __restrict__ v, const u16* __restrict__ Vg,
        const float* __restrict__ spart, const u16* __restrict__ wt,
        const float* __restrict__ b_o, u16* __restrict__ v2) {
    __shared__ float attn[4][16][16];
    __shared__ __align__(16) u16 stg[8 * 2176];   // per-wave 16 x pitch 136
    int tid = threadIdx.x;
    int bid = blockIdx.x;              // 512
    int b = bid >> 6, n = (bid >> 2) & 15, qtr = bid & 3;
    int wi = n >> 2, wj = n & 3;
    int wtb = (b * 16 + n) * 16;

    if (tid < 64) {
        int h = tid >> 4, t = tid & 15;
        int it = wi * 4 + (t >> 2) , jt = wj * 4 + (t & 3);
        int rt = region3(it) * 3 + region3(jt);
        const float* sp0 = spart + (size_t)(((0 + b) * 16 + n) * 4 + h) * 256 + t * 16;
        const float* sp1 = spart + (size_t)(((8 + b) * 16 + n) * 4 + h) * 256 + t * 16;
        float vals[16]; float mx = -1e30f;
        for (int s = 0; s < 16; s++) {
            int is = wi * 4 + (s >> 2), js = wj * 4 + (s & 3);
            int rs = region3(is) * 3 + region3(js);
            float sc = (sp0[s] + sp1[s]) * SCALE + (rs == rt ? 0.f : -1e9f);
            vals[s] = sc; mx = fmaxf(mx, sc);
        }
        float sum = 0.f;
        for (int s = 0; s < 16; s++) { vals[s] = __expf(vals[s] - mx); sum += vals[s]; }
        float inv = 1.f / sum;
        for (int s = 0; s < 16; s++) attn[h][t][s] = vals[s] * inv;
    }
    __syncthreads();                   // the ONLY block barrier

    int lane = tid & 63, wave = tid >> 6;
    int lrow = lane & 15, quad = lane >> 4;
    const u16* WoT = wt + 3 * 16384;
    u16* stgw = stg + wave * 2176;
    int t0 = wave * 2, t1 = t0 + 1;

    for (int sub = 0; sub < 4; sub++) {
        int xyb = qtr * 64 + sub * 16;
        // PV: V fragments direct from global (L2-resident per block)
        bf16x8 pa[2][4];
        #pragma unroll
        for (int kt = 0; kt < 4; kt++) {
            float oa[8], ob[8];
            #pragma unroll
            for (int j = 0; j < 8; j++) { oa[j] = 0.f; ob[j] = 0.f; }
            #pragma unroll
            for (int s = 0; s < 16; s++) {
                u16x8 vv = *(const u16x8*)&Vg[(size_t)(wtb + s) * 32768 +
                                              (size_t)(xyb + lrow) * 128 + kt * 32 + quad * 8];
                float a0 = attn[kt][t0][s], a1 = attn[kt][t1][s];
                #pragma unroll
                for (int j = 0; j < 8; j++) {
                    float x = bf2f(vv[j]);
                    oa[j] = fmaf(a0, x, oa[j]);
                    ob[j] = fmaf(a1, x, ob[j]);
                }
            }
            u16x8 ua, ub;
            #pragma unroll
            for (int j = 0; j < 8; j++) { ua[j] = f2bf(oa[j]); ub[j] = f2bf(ob[j]); }
            pa[0][kt] = u2b(ua); pa[1][kt] = u2b(ub);
        }
        // Wo GEMM + residual, per token (mi) to cap register pressure
        #pragma unroll
        for (int mi = 0; mi < 2; mi++) {
            f32x4 acc[8];
            #pragma unroll
            for (int nt = 0; nt < 8; nt++) acc[nt] = (f32x4){0.f, 0.f, 0.f, 0.f};
            #pragma unroll
            for (int kt = 0; kt < 4; kt++) {
                #pragma unroll
                for (int nt = 0; nt < 8; nt++) {
                    bf16x8 bfr = *(const bf16x8*)&WoT[(nt * 16 + lrow) * 128 + kt * 32 + quad * 8];
                    acc[nt] = MFMA(pa[mi][kt], bfr, acc[nt]);
                }
            }
            int mt = wave * 2 + mi;        // token t within window
            int sd = (((wi * 4 + (mt >> 2) + 2) & 15) << 4) | ((wj * 4 + (mt & 3) + 2) & 15);
            size_t tokbase = (size_t)(b * 256 + sd) * 32768;
            #pragma unroll
            for (int nt = 0; nt < 8; nt++) {
                int cc = nt * 16 + lrow;
                float bv = b_o[cc];
                float4 res = *(const float4*)&v[tokbase + (size_t)cc * 256 + xyb + quad * 4];
                stgw[(quad * 4 + 0) * 136 + cc] = f2bf(acc[nt][0] + bv + res.x);
                stgw[(quad * 4 + 1) * 136 + cc] = f2bf(acc[nt][1] + bv + res.y);
                stgw[(quad * 4 + 2) * 136 + cc] = f2bf(acc[nt][2] + bv + res.z);
                stgw[(quad * 4 + 3) * 136 + cc] = f2bf(acc[nt][3] + bv + res.w);
            }
            // wave-local staging: no barrier needed
            size_t obase = tokbase + (size_t)xyb * 128;
            #pragma unroll
            for (int ro = 0; ro < 4; ro++) {
                int flat = ro * 512 + lane * 8;
                *(u16x8*)&v2[obase + flat] =
                    *(const u16x8*)&stgw[(flat >> 7) * 136 + (flat & 127)];
            }
        }
    }
}

// ---------------------------------------------------------------------------
// K6: per token: stats streamed from global (shfl+LDS reduce), GEMM1 with
//     A loaded+normalized direct from global, gelu -> Hbuf (wave-local),
//     GEMM2 (B direct), + raw residual (L2-hot) -> out f32 [c][xy].
//     LDS ~79KB -> 2 blocks/CU; 2 barriers total.
// ---------------------------------------------------------------------------
__global__ __launch_bounds__(512, 4) void k6_mlp(
        const u16* __restrict__ v2, const u16* __restrict__ wt,
        const float* __restrict__ b1, const float* __restrict__ b2,
        float* __restrict__ out) {
    __shared__ __align__(16) u16 Hbuf[256 * 136];
    __shared__ float red[2][8][128];
    __shared__ float stats[2][128];
    int tid = threadIdx.x;
    size_t tok = blockIdx.x;
    const u16* src = v2 + tok * 32768;
    int wave = tid >> 6, lane = tid & 63;

    // stats: stream contiguous u16x8; lane owns 8 consecutive c
    {
        float s[8], q[8];
        #pragma unroll
        for (int j = 0; j < 8; j++) { s[j] = 0.f; q[j] = 0.f; }
        #pragma unroll
        for (int it = 0; it < 8; it++) {
            u16x8 u = *(const u16x8*)&src[(it * 512 + tid) * 8];
            #pragma unroll
            for (int j = 0; j < 8; j++) {
                float x = bf2f(u[j]);
                s[j] += x; q[j] += x * x;
            }
        }
        // reduce the 4 lane-groups sharing the same c-range (lane^16, lane^32)
        #pragma unroll
        for (int j = 0; j < 8; j++) {
            s[j] += __shfl_xor(s[j], 16); s[j] += __shfl_xor(s[j], 32);
            q[j] += __shfl_xor(q[j], 16); q[j] += __shfl_xor(q[j], 32);
        }
        if (lane < 16) {
            #pragma unroll
            for (int j = 0; j < 8; j++) {
                red[0][wave][lane * 8 + j] = s[j];
                red[1][wave][lane * 8 + j] = q[j];
            }
        }
    }
    __syncthreads();
    if (tid < 128) {
        int c = tid;
        float s = 0.f, q = 0.f;
        #pragma unroll
        for (int w = 0; w < 8; w++) { s += red[0][w][c]; q += red[1][w][c]; }
        float mean = s * (1.f / 256.f);
        float var = q * (1.f / 256.f) - mean * mean;
        float a = rsqrtf(var + EPSf);
        stats[0][c] = a; stats[1][c] = -mean * a;
    }
    __syncthreads();

    int lrow = lane & 15, quad = lane >> 4;
    const u16* W1T = wt + 4 * 16384;
    const u16* W2T = wt + 5 * 16384;

    // GEMM1: A direct from global + in-register normalize; gelu -> Hbuf
    #pragma unroll
    for (int mi = 0; mi < 2; mi++) {
        int mt = wave * 2 + mi;
        bf16x8 afr[4];
        #pragma unroll
        for (int kt = 0; kt < 4; kt++) {
            u16x8 raw = *(const u16x8*)&src[(mt * 16 + lrow) * 128 + kt * 32 + quad * 8];
            u16x8 o;
            #pragma unroll
            for (int j = 0; j < 8; j++) {
                int c = kt * 32 + quad * 8 + j;
                o[j] = f2bf(fmaf(bf2f(raw[j]), stats[0][c], stats[1][c]));
            }
            afr[kt] = u2b(o);
        }
        f32x4 acc[8];
        #pragma unroll
        for (int nt = 0; nt < 8; nt++) acc[nt] = (f32x4){0.f, 0.f, 0.f, 0.f};
        #pragma unroll
        for (int kt = 0; kt < 4; kt++) {
            #pragma unroll
            for (int nt = 0; nt < 8; nt++) {
                bf16x8 bfr = *(const bf16x8*)&W1T[(nt * 16 + lrow) * 128 + kt * 32 + quad * 8];
                acc[nt] = MFMA(afr[kt], bfr, acc[nt]);
            }
        }
        #pragma unroll
        for (int nt = 0; nt < 8; nt++) {
            int c = nt * 16 + lrow;
            float bv = b1[c];
            #pragma unroll
            for (int r = 0; r < 4; r++) {
                float x = acc[nt][r] + bv;
                Hbuf[(mt * 16 + quad * 4 + r) * 136 + c] = f2bf(gelu_f(x));
            }
        }
    }
    // H rows are wave-local -> no barrier
    #pragma unroll
    for (int mi = 0; mi < 2; mi++) {
        int mt = wave * 2 + mi;
        bf16x8 afr[4];
        #pragma unroll
        for (int kt = 0; kt < 4; kt++)
            afr[kt] = *(const bf16x8*)&Hbuf[(mt * 16 + lrow) * 136 + kt * 32 + quad * 8];
        f32x4 acc[8];
        #pragma unroll
        for (int nt = 0; nt < 8; nt++) acc[nt] = (f32x4){0.f, 0.f, 0.f, 0.f};
        #pragma unroll
        for (int kt = 0; kt < 4; kt++) {
            #pragma unroll
            for (int nt = 0; nt < 8; nt++) {
                bf16x8 bfr = *(const bf16x8*)&W2T[(nt * 16 + lrow) * 128 + kt * 32 + quad * 8];
                acc[nt] = MFMA(afr[kt], bfr, acc[nt]);
            }
        }
        #pragma unroll
        for (int nt = 0; nt < 8; nt++) {
            int c = nt * 16 + lrow;
            float bv = b2[c];
            f32x4 o4;
            #pragma unroll
            for (int r = 0; r < 4; r++) {
                int m = mt * 16 + quad * 4 + r;
                o4[r] = acc[nt][r] + bv + bf2f(src[m * 128 + c]);   // raw residual (L2-hot)
            }
            *(f32x4*)&out[tok * 32768 + (size_t)c * 256 + mt * 16 + quad * 4] = o4;
        }
    }
}

// ---------------------------------------------------------------------------
extern "C" void kernel_launch(void* const* d_in, const int* in_sizes, int n_in,
                              void* d_out, int out_size, void* d_ws, size_t ws_size,
                              hipStream_t stream) {
    const float* v   = (const float*)d_in[0];
    const float* w_q = (const float*)d_in[1];
    const float* b_q = (const float*)d_in[2];
    const float* w_k = (const float*)d_in[3];
    const float* b_k = (const float*)d_in[4];
    const float* w_v = (const float*)d_in[5];
    const float* b_v = (const float*)d_in[6];
    const float* w_o = (const float*)d_in[7];
    const float* b_o = (const float*)d_in[8];
    const float* w1  = (const float*)d_in[9];
    const float* b1  = (const float*)d_in[10];
    const float* w2  = (const float*)d_in[11];
    const float* b2  = (const float*)d_in[12];

    // workspace layout (~135.5 MB):
    //   wt    : [0, 196608)            6 x 128x128 bf16 transposed weights
    //   spart : [196608, 1245184)      2*8*16*4*256 floats = 1 MB partial scores
    //   Qg/v2 : [1245184, +134217728)  Q (k2->k3), then v2 overlay (k4->k6)
    u16*   wt    = (u16*)d_ws;
    float* spart = (float*)((char*)d_ws + 196608);
    u16*   Qg    = (u16*)((char*)d_ws + 1245184);
    u16*   v2    = Qg;                                     // overlays Q (dead after k3)
    // d_out doubles as scratch for V and K (dead before k6 writes):
    u16*   Vg    = (u16*)d_out;
    u16*   Kg    = (u16*)d_out + 67108864;
    float* out   = (float*)d_out;

    kw_prep  <<<6,    256,  0, stream>>>(w_q, w_k, w_v, w_o, w1, w2, wt);
    k2_qkv   <<<2048, 512,  0, stream>>>(v, wt, b_q, b_k, b_v, Qg, Kg, Vg);
    k3_scores<<<256,  1024, 0, stream>>>(Qg, Kg, spart);
    k4_attnout<<<512, 512,  0, stream>>>(v, Vg, spart, wt, b_o, v2);
    k6_mlp   <<<2048, 512,  0, stream>>>(v2, wt, b1, b2, out);
}